// Round 2
// baseline (216.750 us; speedup 1.0000x reference)
//
#include <hip/hip_runtime.h>
#include <hip/hip_bf16.h>
#include <math.h>

// Problem constants (match reference)
constexpr int KB_B  = 16;
constexpr int KB_H  = 12;
constexpr int KB_P  = 256;
constexpr int KB_D  = 64;
constexpr int KB_NF = 8;
constexpr int KB_NROWS = KB_B * KB_H * KB_P;      // 49152 rows per tensor

__device__ inline float ka_lanebcast(float v, int l) {
    return __int_as_float(__builtin_amdgcn_readlane(__float_as_int(v), l));
}

// ---------------------------------------------------------------------------
// Kernel A: sig_rowsum for q and k.
//   base = silu(x) @ base_weight.T           [row, d]
//   fk   = sum_f coef[d,f] * sin(grid[f]*x[d])
//   f    = fk*scale_sp + base*scale_base
//   out[row] = sum_d sigmoid(f[row,d])
// Block = 256 threads = 4 waves; each wave handles one row (64 dims).
// base_weight held in 64 VGPRs per lane (row d = lane); silu broadcast via
// v_readlane -> matmul is pure VALU (no LDS traffic at all).
// ---------------------------------------------------------------------------
__global__ __launch_bounds__(256) void ka_sig_rowsum_kernel(
    const float* __restrict__ q, const float* __restrict__ k,
    const float* __restrict__ grid_v, const float* __restrict__ bw,
    const float* __restrict__ coef, const float* __restrict__ scale_base,
    const float* __restrict__ scale_sp,
    float* __restrict__ sq, float* __restrict__ sk)
{
    const int tid  = threadIdx.x;
    const int lane = tid & 63;
    const int wv   = tid >> 6;

    // base_weight row `lane` into registers (16x float4, L1-resident)
    float4 w4[16];
    const float4* bwrow = reinterpret_cast<const float4*>(bw + (size_t)lane * KB_D);
#pragma unroll
    for (int j = 0; j < 16; ++j) w4[j] = bwrow[j];
    const float* w = reinterpret_cast<const float*>(w4);

    // per-lane coef[d=lane, 0..7]
    const float4* c4 = reinterpret_cast<const float4*>(coef + lane * KB_NF);
    float4 ca = c4[0], cb = c4[1];
    float cf[KB_NF] = {ca.x, ca.y, ca.z, ca.w, cb.x, cb.y, cb.z, cb.w};
    float gr[KB_NF];
#pragma unroll
    for (int f = 0; f < KB_NF; ++f) gr[f] = grid_v[f];

    const int rowg = blockIdx.x * 4 + wv;               // 0 .. 2*NROWS-1
    const bool is_q = (rowg < KB_NROWS);
    const int row = is_q ? rowg : (rowg - KB_NROWS);
    const float* __restrict__ x = is_q ? q : k;
    float* __restrict__ outp = is_q ? sq : sk;

    const float xv = x[(size_t)row * KB_D + lane];
    const float sigx = 1.f / (1.f + __expf(-xv));
    const float silu = xv * sigx;

    // base[lane] = sum_e silu[e] * W[lane][e]  -- broadcast silu via readlane
    float base = 0.f;
#pragma unroll
    for (int e = 0; e < 64; ++e)
        base = fmaf(ka_lanebcast(silu, e), w[e], base);

    float fk = 0.f;
#pragma unroll
    for (int f = 0; f < KB_NF; ++f)
        fk = fmaf(cf[f], __sinf(gr[f] * xv), fk);

    const int hp = row % (KB_H * KB_P);                 // scale tensors are [1,H,P,D]
    const int sidx = hp * KB_D + lane;
    const float fval = fk * scale_sp[sidx] + base * scale_base[sidx];
    float sg = 1.f / (1.f + __expf(-fval));

    // full-wave (64-lane) reduction
#pragma unroll
    for (int off = 32; off; off >>= 1) sg += __shfl_down(sg, off);
    if (lane == 0) outp[row] = sg;
}

// ---------------------------------------------------------------------------
// phi helpers (double): phi(z) = (e^z - 1)/z, phi'(z)
// ---------------------------------------------------------------------------
__device__ inline double ka_phi(double z) {
    if (fabs(z) < 1e-5)
        return 1.0 + z * (0.5 + z * (1.0 / 6.0 + z * (1.0 / 24.0)));
    return (exp(z) - 1.0) / z;
}
__device__ inline double ka_phip(double z) {
    if (fabs(z) < 1e-4)
        return 0.5 + z * (1.0 / 3.0 + z * 0.125);
    return (exp(z) * (z - 1.0) + 1.0) / (z * z);
}

// ---------------------------------------------------------------------------
// Kernel B: per (b,h):
//   r[p'] = sum_j lin_w[p',j]
//   v[p'] = sum_j lin_w[p',j]*sk[j] + lin_b[p']
//   M = a r^T + 1 v^T  (a = sq[b,h,:]),  exp(M) = I + U phi(S) W^T,
//   S = [[r.a, r.1],[v.a, v.1]]  (2x2, double)
//   k_new = k + a * y1 + y2,  [y1;y2] = phi(S) * (W^T k)
// One block of 256 threads per (b,h).
// ---------------------------------------------------------------------------
__global__ __launch_bounds__(256) void ka_rank2_expm_kernel(
    const float* __restrict__ k, const float* __restrict__ lin_w,
    const float* __restrict__ lin_b, const float* __restrict__ sq,
    const float* __restrict__ sk, float* __restrict__ out_k)
{
    const int bh = blockIdx.x;            // 0..191
    const int t = threadIdx.x;
    const int lane = t & 63;
    const int wv = t >> 6;

    __shared__ float a_sh[KB_P], sk_sh[KB_P], r_sh[KB_P], v_sh[KB_P];
    __shared__ float t1_sh[4][64], t2_sh[4][64];
    __shared__ double red_sh[4][4];
    __shared__ double G_sh[4];

    a_sh[t]  = sq[bh * KB_P + t];
    sk_sh[t] = sk[bh * KB_P + t];
    __syncthreads();

    // r[t], v[t]: stream this thread's lin_w row (1KB) as float4
    float racc = 0.f, vacc = 0.f;
    const float4* wrow = reinterpret_cast<const float4*>(lin_w + (size_t)t * KB_P);
#pragma unroll 4
    for (int j4 = 0; j4 < KB_P / 4; ++j4) {
        float4 w = wrow[j4];
        const float* skp = &sk_sh[j4 * 4];
        racc += w.x + w.y + w.z + w.w;
        vacc = fmaf(w.x, skp[0], vacc);
        vacc = fmaf(w.y, skp[1], vacc);
        vacc = fmaf(w.z, skp[2], vacc);
        vacc = fmaf(w.w, skp[3], vacc);
    }
    r_sh[t] = racc;
    v_sh[t] = vacc + lin_b[t];
    __syncthreads();

    // S entries: 4 dot products over P=256 in double
    double c0 = (double)r_sh[t] * (double)a_sh[t];
    double c1 = (double)r_sh[t];
    double c2 = (double)v_sh[t] * (double)a_sh[t];
    double c3 = (double)v_sh[t];
#pragma unroll
    for (int off = 32; off; off >>= 1) {
        c0 += __shfl_down(c0, off);
        c1 += __shfl_down(c1, off);
        c2 += __shfl_down(c2, off);
        c3 += __shfl_down(c3, off);
    }
    if (lane == 0) {
        red_sh[wv][0] = c0; red_sh[wv][1] = c1;
        red_sh[wv][2] = c2; red_sh[wv][3] = c3;
    }

    // t1[d] = sum_p r[p]*k[p,d],  t2[d] = sum_p v[p]*k[p,d]  (partial per wave)
    const float* kbh = k + (size_t)bh * KB_P * KB_D;
    float t1 = 0.f, t2 = 0.f;
    for (int p = wv; p < KB_P; p += 4) {
        float kv = kbh[p * KB_D + lane];
        t1 = fmaf(r_sh[p], kv, t1);
        t2 = fmaf(v_sh[p], kv, t2);
    }
    t1_sh[wv][lane] = t1;
    t2_sh[wv][lane] = t2;
    __syncthreads();

    if (t == 0) {
        double s11 = 0, s12 = 0, s21 = 0, s22 = 0;
        for (int w2 = 0; w2 < 4; ++w2) {
            s11 += red_sh[w2][0]; s12 += red_sh[w2][1];
            s21 += red_sh[w2][2]; s22 += red_sh[w2][3];
        }
        const double tr = s11 + s22;
        const double det = s11 * s22 - s12 * s21;
        const double mu = 0.5 * tr;
        const double disc = mu * mu - det;
        double alpha, beta;
        if (disc >= 0.0) {
            const double w = sqrt(disc);
            if (w > 1e-7 * (1.0 + fabs(mu))) {
                const double l1 = mu + w, l2 = mu - w;
                const double p1 = ka_phi(l1), p2 = ka_phi(l2);
                beta = (p1 - p2) / (2.0 * w);
                alpha = p1 - beta * l1;
            } else {
                beta = ka_phip(mu);
                alpha = ka_phi(mu) - beta * mu;
            }
        } else {
            const double w = sqrt(-disc);      // eigenvalues mu +- i*w, w > 0
            const double em = exp(mu);
            const double nre = em * cos(w) - 1.0;
            const double nim = em * sin(w);
            const double den = mu * mu + w * w;
            const double pre = (nre * mu + nim * w) / den;
            const double pim = (nim * mu - nre * w) / den;
            beta = pim / w;
            alpha = pre - beta * mu;
        }
        G_sh[0] = alpha + beta * s11;   // G = alpha*I + beta*S
        G_sh[1] = beta * s12;
        G_sh[2] = beta * s21;
        G_sh[3] = alpha + beta * s22;
    }
    __syncthreads();

    // total t1/t2 for this lane's d, then y = G * t
    const float t1tot = t1_sh[0][lane] + t1_sh[1][lane] + t1_sh[2][lane] + t1_sh[3][lane];
    const float t2tot = t2_sh[0][lane] + t2_sh[1][lane] + t2_sh[2][lane] + t2_sh[3][lane];
    const float G00 = (float)G_sh[0], G01 = (float)G_sh[1];
    const float G10 = (float)G_sh[2], G11v = (float)G_sh[3];
    const float y1 = G00 * t1tot + G01 * t2tot;
    const float y2 = G10 * t1tot + G11v * t2tot;

    float* obh = out_k + (size_t)bh * KB_P * KB_D;
    for (int p = wv; p < KB_P; p += 4) {
        const float kv = kbh[p * KB_D + lane];
        obh[p * KB_D + lane] = kv + a_sh[p] * y1 + y2;
    }
}

// ---------------------------------------------------------------------------
extern "C" void kernel_launch(void* const* d_in, const int* in_sizes, int n_in,
                              void* d_out, int out_size, void* d_ws, size_t ws_size,
                              hipStream_t stream) {
    const float* q          = (const float*)d_in[0];
    const float* k          = (const float*)d_in[1];
    // d_in[2] = scale (unused by forward)
    const float* grid_v     = (const float*)d_in[3];
    const float* bw         = (const float*)d_in[4];
    const float* coef       = (const float*)d_in[5];
    const float* scale_base = (const float*)d_in[6];
    const float* scale_sp   = (const float*)d_in[7];
    const float* lin_w      = (const float*)d_in[8];
    const float* lin_b      = (const float*)d_in[9];

    float* out = (float*)d_out;
    const size_t tensor_elems = (size_t)KB_B * KB_H * KB_P * KB_D;  // 3,145,728

    float* sq = (float*)d_ws;                 // KB_NROWS floats
    float* sk = sq + KB_NROWS;                // KB_NROWS floats

    // Output 0: q passthrough
    hipMemcpyAsync(out, q, tensor_elems * sizeof(float),
                   hipMemcpyDeviceToDevice, stream);

    // sq / sk
    ka_sig_rowsum_kernel<<<2 * KB_NROWS / 4, 256, 0, stream>>>(
        q, k, grid_v, bw, coef, scale_base, scale_sp, sq, sk);

    // rank-2 expm + k_new
    ka_rank2_expm_kernel<<<KB_B * KB_H, 256, 0, stream>>>(
        k, lin_w, lin_b, sq, sk, out + tensor_elems);
}

// Round 3
// 59.830 us; speedup vs baseline: 3.6227x; 3.6227x over previous
//
#include <hip/hip_runtime.h>
#include <hip/hip_bf16.h>
#include <math.h>

// Problem constants (match reference)
constexpr int KB_B  = 16;
constexpr int KB_H  = 12;
constexpr int KB_P  = 256;
constexpr int KB_D  = 64;
constexpr int KB_NF = 8;
constexpr int KB_NROWS = KB_B * KB_H * KB_P;      // 49152 rows per tensor

typedef __bf16 bf16x8 __attribute__((ext_vector_type(8)));
typedef float  f32x4  __attribute__((ext_vector_type(4)));

__device__ inline __bf16 ka_silu_bf(float f) {
    return (__bf16)(f / (1.f + __expf(-f)));
}

// ---------------------------------------------------------------------------
// Kernel A: sig_rowsum for q and k, MFMA edition + fused q passthrough.
//   base = silu(x) @ base_weight.T  via mfma_f32_16x16x32_bf16 (2 k-steps,
//   4 n-tiles per wave, 16 rows per wave). Elementwise sin/sigmoid done in
//   the MFMA C layout (col=lane&15, row=(lane>>4)*4+reg). No LDS.
// Block = 256 threads = 4 waves; each block covers 64 rows of one tensor.
// ---------------------------------------------------------------------------
__global__ __launch_bounds__(256, 4) void ka_sig_rowsum_mfma(
    const float* __restrict__ q, const float* __restrict__ k,
    const float* __restrict__ grid_v, const float* __restrict__ bw,
    const float* __restrict__ coef, const float* __restrict__ scale_base,
    const float* __restrict__ scale_sp,
    float* __restrict__ sq, float* __restrict__ sk, float* __restrict__ out_q)
{
    const int tid  = threadIdx.x;
    const int lane = tid & 63;
    const int wv   = tid >> 6;
    const int l15  = lane & 15;
    const int lg   = lane >> 4;                     // 0..3

    const bool is_q = blockIdx.x < (KB_NROWS / 64);
    const int  blk  = is_q ? blockIdx.x : blockIdx.x - KB_NROWS / 64;
    const int  rowbase = blk * 64 + wv * 16;        // row within tensor
    const float* __restrict__ x    = is_q ? q : k;
    float* __restrict__       outp = is_q ? sq : sk;

    // grid (uniform -> SGPR)
    const float g0 = grid_v[0], g1 = grid_v[1], g2 = grid_v[2], g3 = grid_v[3];
    const float g4 = grid_v[4], g5 = grid_v[5], g6 = grid_v[6], g7 = grid_v[7];

    // ---- B fragments: B[k=e][n=d] = bw[d][e], lane l -> (k=8*lg+j, n=l15) ----
    bf16x8 bfrag[4][2];
#pragma unroll
    for (int nt = 0; nt < 4; ++nt) {
        const float* bp = bw + (size_t)(nt * 16 + l15) * KB_D + 8 * lg;
#pragma unroll
        for (int h = 0; h < 2; ++h) {
            float4 p0 = *reinterpret_cast<const float4*>(bp + 32 * h);
            float4 p1 = *reinterpret_cast<const float4*>(bp + 32 * h + 4);
            bfrag[nt][h][0] = (__bf16)p0.x; bfrag[nt][h][1] = (__bf16)p0.y;
            bfrag[nt][h][2] = (__bf16)p0.z; bfrag[nt][h][3] = (__bf16)p0.w;
            bfrag[nt][h][4] = (__bf16)p1.x; bfrag[nt][h][5] = (__bf16)p1.y;
            bfrag[nt][h][6] = (__bf16)p1.z; bfrag[nt][h][7] = (__bf16)p1.w;
        }
    }

    // ---- A fragments: A[m=l15][k=8*lg+j] = silu(x[rowbase+m][k]) ----
    const float* xp = x + (size_t)(rowbase + l15) * KB_D + 8 * lg;
    bf16x8 afrag[2];
#pragma unroll
    for (int h = 0; h < 2; ++h) {
        float4 p0 = *reinterpret_cast<const float4*>(xp + 32 * h);
        float4 p1 = *reinterpret_cast<const float4*>(xp + 32 * h + 4);
        afrag[h][0] = ka_silu_bf(p0.x); afrag[h][1] = ka_silu_bf(p0.y);
        afrag[h][2] = ka_silu_bf(p0.z); afrag[h][3] = ka_silu_bf(p0.w);
        afrag[h][4] = ka_silu_bf(p1.x); afrag[h][5] = ka_silu_bf(p1.y);
        afrag[h][6] = ka_silu_bf(p1.z); afrag[h][7] = ka_silu_bf(p1.w);
    }

    // ---- MFMA: acc[nt] = silu(X) @ bw^T tile ----
    f32x4 acc[4];
#pragma unroll
    for (int nt = 0; nt < 4; ++nt) {
        acc[nt] = (f32x4){0.f, 0.f, 0.f, 0.f};
        acc[nt] = __builtin_amdgcn_mfma_f32_16x16x32_bf16(afrag[0], bfrag[nt][0], acc[nt], 0, 0, 0);
        acc[nt] = __builtin_amdgcn_mfma_f32_16x16x32_bf16(afrag[1], bfrag[nt][1], acc[nt], 0, 0, 0);
    }

    // ---- elementwise in C layout: row = rowbase + lg*4 + reg, d = nt*16+l15 ----
    const int row0 = rowbase + lg * 4;
    const int hp0  = row0 % (KB_H * KB_P);          // 3072 | rows aligned to 4
    float rowsum[4] = {0.f, 0.f, 0.f, 0.f};

#pragma unroll
    for (int nt = 0; nt < 4; ++nt) {
        const int d = nt * 16 + l15;
        float4 c0 = *reinterpret_cast<const float4*>(coef + d * KB_NF);
        float4 c1 = *reinterpret_cast<const float4*>(coef + d * KB_NF + 4);
#pragma unroll
        for (int reg = 0; reg < 4; ++reg) {
            const int row = row0 + reg;
            const float xv = x[(size_t)row * KB_D + d];
            if (is_q) out_q[(size_t)row * KB_D + d] = xv;
            float fk = c0.x * __sinf(g0 * xv);
            fk = fmaf(c0.y, __sinf(g1 * xv), fk);
            fk = fmaf(c0.z, __sinf(g2 * xv), fk);
            fk = fmaf(c0.w, __sinf(g3 * xv), fk);
            fk = fmaf(c1.x, __sinf(g4 * xv), fk);
            fk = fmaf(c1.y, __sinf(g5 * xv), fk);
            fk = fmaf(c1.z, __sinf(g6 * xv), fk);
            fk = fmaf(c1.w, __sinf(g7 * xv), fk);
            const int sidx = (hp0 + reg) * KB_D + d;
            const float fv = fk * scale_sp[sidx] + acc[nt][reg] * scale_base[sidx];
            rowsum[reg] += 1.f / (1.f + __expf(-fv));
        }
    }

    // ---- reduce across the 16-lane group, write per-row sums ----
#pragma unroll
    for (int reg = 0; reg < 4; ++reg) {
        float s = rowsum[reg];
        s += __shfl_xor(s, 1);
        s += __shfl_xor(s, 2);
        s += __shfl_xor(s, 4);
        s += __shfl_xor(s, 8);
        if (l15 == 0) outp[row0 + reg] = s;
    }
}

// ---------------------------------------------------------------------------
// phi helpers (double): phi(z) = (e^z - 1)/z, phi'(z)
// ---------------------------------------------------------------------------
__device__ inline double ka_phi(double z) {
    if (fabs(z) < 1e-5)
        return 1.0 + z * (0.5 + z * (1.0 / 6.0 + z * (1.0 / 24.0)));
    return (exp(z) - 1.0) / z;
}
__device__ inline double ka_phip(double z) {
    if (fabs(z) < 1e-4)
        return 0.5 + z * (1.0 / 3.0 + z * 0.125);
    return (exp(z) * (z - 1.0) + 1.0) / (z * z);
}

// ---------------------------------------------------------------------------
// Kernel B: per (b,h):
//   r[p'] = sum_j lin_w[p',j]
//   v[p'] = sum_j lin_w[p',j]*sk[j] + lin_b[p']
//   M = a r^T + 1 v^T  (a = sq[b,h,:]),  exp(M) = I + U phi(S) W^T,
//   S = [[r.a, r.1],[v.a, v.1]]  (2x2, double)
//   k_new = k + a * y1 + y2,  [y1;y2] = phi(S) * (W^T k)
// One block of 256 threads per (b,h).
// ---------------------------------------------------------------------------
__global__ __launch_bounds__(256) void ka_rank2_expm_kernel(
    const float* __restrict__ k, const float* __restrict__ lin_w,
    const float* __restrict__ lin_b, const float* __restrict__ sq,
    const float* __restrict__ sk, float* __restrict__ out_k)
{
    const int bh = blockIdx.x;            // 0..191
    const int t = threadIdx.x;
    const int lane = t & 63;
    const int wv = t >> 6;

    __shared__ float a_sh[KB_P], sk_sh[KB_P], r_sh[KB_P], v_sh[KB_P];
    __shared__ float t1_sh[4][64], t2_sh[4][64];
    __shared__ double red_sh[4][4];
    __shared__ double G_sh[4];

    a_sh[t]  = sq[bh * KB_P + t];
    sk_sh[t] = sk[bh * KB_P + t];
    __syncthreads();

    // r[t], v[t]: stream this thread's lin_w row (1KB) as float4
    float racc = 0.f, vacc = 0.f;
    const float4* wrow = reinterpret_cast<const float4*>(lin_w + (size_t)t * KB_P);
#pragma unroll 4
    for (int j4 = 0; j4 < KB_P / 4; ++j4) {
        float4 w = wrow[j4];
        const float* skp = &sk_sh[j4 * 4];
        racc += w.x + w.y + w.z + w.w;
        vacc = fmaf(w.x, skp[0], vacc);
        vacc = fmaf(w.y, skp[1], vacc);
        vacc = fmaf(w.z, skp[2], vacc);
        vacc = fmaf(w.w, skp[3], vacc);
    }
    r_sh[t] = racc;
    v_sh[t] = vacc + lin_b[t];
    __syncthreads();

    // S entries: 4 dot products over P=256 in double
    double c0 = (double)r_sh[t] * (double)a_sh[t];
    double c1 = (double)r_sh[t];
    double c2 = (double)v_sh[t] * (double)a_sh[t];
    double c3 = (double)v_sh[t];
#pragma unroll
    for (int off = 32; off; off >>= 1) {
        c0 += __shfl_down(c0, off);
        c1 += __shfl_down(c1, off);
        c2 += __shfl_down(c2, off);
        c3 += __shfl_down(c3, off);
    }
    if (lane == 0) {
        red_sh[wv][0] = c0; red_sh[wv][1] = c1;
        red_sh[wv][2] = c2; red_sh[wv][3] = c3;
    }

    // t1[d] = sum_p r[p]*k[p,d],  t2[d] = sum_p v[p]*k[p,d]  (partial per wave)
    const float* kbh = k + (size_t)bh * KB_P * KB_D;
    float t1 = 0.f, t2 = 0.f;
    for (int p = wv; p < KB_P; p += 4) {
        float kv = kbh[p * KB_D + lane];
        t1 = fmaf(r_sh[p], kv, t1);
        t2 = fmaf(v_sh[p], kv, t2);
    }
    t1_sh[wv][lane] = t1;
    t2_sh[wv][lane] = t2;
    __syncthreads();

    if (t == 0) {
        double s11 = 0, s12 = 0, s21 = 0, s22 = 0;
        for (int w2 = 0; w2 < 4; ++w2) {
            s11 += red_sh[w2][0]; s12 += red_sh[w2][1];
            s21 += red_sh[w2][2]; s22 += red_sh[w2][3];
        }
        const double tr = s11 + s22;
        const double det = s11 * s22 - s12 * s21;
        const double mu = 0.5 * tr;
        const double disc = mu * mu - det;
        double alpha, beta;
        if (disc >= 0.0) {
            const double w = sqrt(disc);
            if (w > 1e-7 * (1.0 + fabs(mu))) {
                const double l1 = mu + w, l2 = mu - w;
                const double p1 = ka_phi(l1), p2 = ka_phi(l2);
                beta = (p1 - p2) / (2.0 * w);
                alpha = p1 - beta * l1;
            } else {
                beta = ka_phip(mu);
                alpha = ka_phi(mu) - beta * mu;
            }
        } else {
            const double w = sqrt(-disc);      // eigenvalues mu +- i*w, w > 0
            const double em = exp(mu);
            const double nre = em * cos(w) - 1.0;
            const double nim = em * sin(w);
            const double den = mu * mu + w * w;
            const double pre = (nre * mu + nim * w) / den;
            const double pim = (nim * mu - nre * w) / den;
            beta = pim / w;
            alpha = pre - beta * mu;
        }
        G_sh[0] = alpha + beta * s11;   // G = alpha*I + beta*S
        G_sh[1] = beta * s12;
        G_sh[2] = beta * s21;
        G_sh[3] = alpha + beta * s22;
    }
    __syncthreads();

    // total t1/t2 for this lane's d, then y = G * t
    const float t1tot = t1_sh[0][lane] + t1_sh[1][lane] + t1_sh[2][lane] + t1_sh[3][lane];
    const float t2tot = t2_sh[0][lane] + t2_sh[1][lane] + t2_sh[2][lane] + t2_sh[3][lane];
    const float G00 = (float)G_sh[0], G01 = (float)G_sh[1];
    const float G10 = (float)G_sh[2], G11v = (float)G_sh[3];
    const float y1 = G00 * t1tot + G01 * t2tot;
    const float y2 = G10 * t1tot + G11v * t2tot;

    float* obh = out_k + (size_t)bh * KB_P * KB_D;
    for (int p = wv; p < KB_P; p += 4) {
        const float kv = kbh[p * KB_D + lane];
        obh[p * KB_D + lane] = kv + a_sh[p] * y1 + y2;
    }
}

// ---------------------------------------------------------------------------
extern "C" void kernel_launch(void* const* d_in, const int* in_sizes, int n_in,
                              void* d_out, int out_size, void* d_ws, size_t ws_size,
                              hipStream_t stream) {
    const float* q          = (const float*)d_in[0];
    const float* k          = (const float*)d_in[1];
    // d_in[2] = scale (unused by forward)
    const float* grid_v     = (const float*)d_in[3];
    const float* bw         = (const float*)d_in[4];
    const float* coef       = (const float*)d_in[5];
    const float* scale_base = (const float*)d_in[6];
    const float* scale_sp   = (const float*)d_in[7];
    const float* lin_w      = (const float*)d_in[8];
    const float* lin_b      = (const float*)d_in[9];

    float* out = (float*)d_out;
    const size_t tensor_elems = (size_t)KB_B * KB_H * KB_P * KB_D;  // 3,145,728

    float* sq = (float*)d_ws;                 // KB_NROWS floats
    float* sk = sq + KB_NROWS;                // KB_NROWS floats

    // sq / sk (+ fused q passthrough into out[0])
    ka_sig_rowsum_mfma<<<2 * KB_NROWS / 64, 256, 0, stream>>>(
        q, k, grid_v, bw, coef, scale_base, scale_sp, sq, sk, out);

    // rank-2 expm + k_new
    ka_rank2_expm_kernel<<<KB_B * KB_H, 256, 0, stream>>>(
        k, lin_w, lin_b, sq, sk, out + tensor_elems);
}